// Round 5
// baseline (1042.173 us; speedup 1.0000x reference)
//
#include <hip/hip_runtime.h>

// GCN: 2x GCNConv + linear scorer.
// N=100000 nodes, F_IN=128, H=32, E=3.2M edges (+ implicit self-loops).
// Self-loops are handled analytically (deg+1, h[i]*dinv[i]^2 term) instead of
// materializing E+N edges.

constexpr int NN  = 100000;
constexpr int FIN = 128;
constexpr int H   = 32;

__global__ void zero_kernel(float4* __restrict__ p, int n4) {
  int stride = gridDim.x * blockDim.x;
  for (int i = blockIdx.x * blockDim.x + threadIdx.x; i < n4; i += stride)
    p[i] = float4{0.f, 0.f, 0.f, 0.f};
}

__global__ void degree_kernel(const int* __restrict__ dst, float* __restrict__ deg, int E) {
  int stride = gridDim.x * blockDim.x;
  for (int e = blockIdx.x * blockDim.x + threadIdx.x; e < E; e += stride)
    atomicAdd(&deg[dst[e]], 1.0f);
}

__global__ void dinv_kernel(const float* __restrict__ deg, float* __restrict__ dinv, int n) {
  int i = blockIdx.x * blockDim.x + threadIdx.x;
  if (i < n) dinv[i] = rsqrtf(deg[i] + 1.0f);  // +1 = self-loop; always > 0
}

// h[i][j] = sum_k x[i][k] * W[k][j]   (K=128, J=32). One thread per output.
// 32 consecutive lanes share one x row (broadcast loads); W staged in LDS.
__global__ void gemm1_kernel(const float* __restrict__ x, const float* __restrict__ W,
                             float* __restrict__ h, int n) {
  __shared__ float Wl[FIN * H];
  for (int t = threadIdx.x; t < FIN * H; t += blockDim.x) Wl[t] = W[t];
  __syncthreads();
  int t = blockIdx.x * blockDim.x + threadIdx.x;
  int i = t >> 5, j = t & 31;
  if (i >= n) return;
  const float4* xr = (const float4*)(x + (size_t)i * FIN);
  float acc = 0.f;
  #pragma unroll 8
  for (int k4 = 0; k4 < FIN / 4; ++k4) {
    float4 v = xr[k4];
    acc += v.x * Wl[(k4 * 4 + 0) * H + j];
    acc += v.y * Wl[(k4 * 4 + 1) * H + j];
    acc += v.z * Wl[(k4 * 4 + 2) * H + j];
    acc += v.w * Wl[(k4 * 4 + 3) * H + j];
  }
  h[t] = acc;  // t == i*H + j
}

// h2[i][j] = sum_k a[i][k] * W[k][j]   (K=32, J=32)
__global__ void gemm2_kernel(const float* __restrict__ a, const float* __restrict__ W,
                             float* __restrict__ h, int n) {
  __shared__ float Wl[H * H];
  for (int t = threadIdx.x; t < H * H; t += blockDim.x) Wl[t] = W[t];
  __syncthreads();
  int t = blockIdx.x * blockDim.x + threadIdx.x;
  int i = t >> 5, j = t & 31;
  if (i >= n) return;
  const float4* ar = (const float4*)(a + (size_t)i * H);
  float acc = 0.f;
  #pragma unroll
  for (int k4 = 0; k4 < H / 4; ++k4) {
    float4 v = ar[k4];
    acc += v.x * Wl[(k4 * 4 + 0) * H + j];
    acc += v.y * Wl[(k4 * 4 + 1) * H + j];
    acc += v.z * Wl[(k4 * 4 + 2) * H + j];
    acc += v.w * Wl[(k4 * 4 + 3) * H + j];
  }
  h[t] = acc;
}

// agg[dst[e]][j] += h[src[e]][j] * dinv[src]*dinv[dst]; one thread per (e,j),
// 32 consecutive lanes = one edge -> coalesced 128B gather + atomic burst.
__global__ void scatter_kernel(const int* __restrict__ src, const int* __restrict__ dst,
                               const float* __restrict__ dinv, const float* __restrict__ h,
                               float* __restrict__ agg, int E) {
  int total = E * H;
  int stride = gridDim.x * blockDim.x;
  for (int t = blockIdx.x * blockDim.x + threadIdx.x; t < total; t += stride) {
    int e = t >> 5, j = t & 31;
    int s = src[e], d = dst[e];
    float w = dinv[s] * dinv[d];
    atomicAdd(&agg[d * H + j], h[s * H + j] * w);
  }
}

// a = relu(agg + h*dinv^2 + b), written in place into agg.
__global__ void post_kernel(float* __restrict__ agg, const float* __restrict__ h,
                            const float* __restrict__ dinv, const float* __restrict__ b, int n) {
  int t = blockIdx.x * blockDim.x + threadIdx.x;
  if (t >= n * H) return;
  int i = t >> 5, j = t & 31;
  float di = dinv[i];
  float v = agg[t] + h[t] * di * di + b[j];
  agg[t] = fmaxf(v, 0.f);
}

// out[i] = sum_j relu(agg2 + h2*dinv^2 + b2)[i][j] * Wfc[j] + bfc
__global__ void final_kernel(const float* __restrict__ agg2, const float* __restrict__ h2,
                             const float* __restrict__ dinv, const float* __restrict__ b2,
                             const float* __restrict__ Wfc, const float* __restrict__ bfc,
                             float* __restrict__ out, int n) {
  int t = blockIdx.x * blockDim.x + threadIdx.x;
  int i = t >> 5, j = t & 31;
  if (i >= n) return;
  float di = dinv[i];
  float v = agg2[t] + h2[t] * di * di + b2[j];
  v = fmaxf(v, 0.f) * Wfc[j];
  #pragma unroll
  for (int m = 16; m; m >>= 1) v += __shfl_xor(v, m, 32);
  if (j == 0) out[i] = v + bfc[0];
}

extern "C" void kernel_launch(void* const* d_in, const int* in_sizes, int n_in,
                              void* d_out, int out_size, void* d_ws, size_t ws_size,
                              hipStream_t stream) {
  const float* x   = (const float*)d_in[0];
  const int*   ei  = (const int*)d_in[1];
  const float* W1  = (const float*)d_in[2];
  const float* b1  = (const float*)d_in[3];
  const float* W2  = (const float*)d_in[4];
  const float* b2  = (const float*)d_in[5];
  const float* Wfc = (const float*)d_in[6];
  const float* bfc = (const float*)d_in[7];
  float* out = (float*)d_out;

  const int E = in_sizes[1] / 2;
  const int* src = ei;
  const int* dst = ei + E;

  // ws layout (floats): [deg N | agg1 N*H | agg2 N*H | dinv N | h N*H]
  float* ws   = (float*)d_ws;
  float* deg  = ws;
  float* agg1 = deg + NN;
  float* agg2 = agg1 + (size_t)NN * H;
  float* dinv = agg2 + (size_t)NN * H;
  float* h    = dinv + NN;

  const int n4 = NN * (1 + 2 * H) / 4;  // zero deg+agg1+agg2 (contiguous)
  const int nb_nh = (NN * H + 255) / 256;

  zero_kernel<<<2048, 256, 0, stream>>>((float4*)ws, n4);
  degree_kernel<<<2048, 256, 0, stream>>>(dst, deg, E);
  dinv_kernel<<<(NN + 255) / 256, 256, 0, stream>>>(deg, dinv, NN);
  gemm1_kernel<<<nb_nh, 256, 0, stream>>>(x, W1, h, NN);
  scatter_kernel<<<2048, 256, 0, stream>>>(src, dst, dinv, h, agg1, E);
  post_kernel<<<nb_nh, 256, 0, stream>>>(agg1, h, dinv, b1, NN);
  gemm2_kernel<<<nb_nh, 256, 0, stream>>>(agg1, W2, h, NN);  // h now = h2
  scatter_kernel<<<2048, 256, 0, stream>>>(src, dst, dinv, h, agg2, E);
  final_kernel<<<nb_nh, 256, 0, stream>>>(agg2, h, dinv, b2, Wfc, bfc, out, NN);
}

// Round 7
// 769.705 us; speedup vs baseline: 1.3540x; 1.3540x over previous
//
#include <hip/hip_runtime.h>

// GCN: 2x GCNConv + linear scorer. N=100000, F_IN=128, H=32, E=3.2M.
// Round 6: scatter+atomicAdd(float) replaced by on-device CSR build + pure
// gather (counters showed 400MB/pass atomic write-through, 24% HBM BW).
// Self-loops handled analytically (deg+1, h[i]*dinv[i]^2 term).

constexpr int NN  = 100000;
constexpr int FIN = 128;
constexpr int H   = 32;
constexpr int SCAN_B = 1024;                       // scan1 block size
constexpr int SCAN_NB = (NN + SCAN_B - 1) / SCAN_B; // 98 blocks

__global__ void zero_int_kernel(int* __restrict__ p, int n) {
  int i = blockIdx.x * blockDim.x + threadIdx.x;
  if (i < n) p[i] = 0;
}

// cnt[d] += 1 per edge (int atomics on 400KB table; L2-resident)
__global__ void hist_kernel(const int* __restrict__ dst, int* __restrict__ cnt, int E) {
  int stride = gridDim.x * blockDim.x;
  for (int e = blockIdx.x * blockDim.x + threadIdx.x; e < E; e += stride)
    atomicAdd(&cnt[dst[e]], 1);
}

// Per-block exclusive scan of cnt -> row_start (partial); block totals -> blksum.
__global__ void scan1_kernel(const int* __restrict__ cnt, int* __restrict__ row_start,
                             int* __restrict__ blksum, int n) {
  __shared__ int sm[2][SCAN_B];
  int tid = threadIdx.x;
  int i = blockIdx.x * SCAN_B + tid;
  int v = (i < n) ? cnt[i] : 0;
  sm[0][tid] = v;
  __syncthreads();
  int cur = 0;
  #pragma unroll
  for (int off = 1; off < SCAN_B; off <<= 1) {   // Hillis-Steele inclusive
    int a = sm[cur][tid];
    if (tid >= off) a += sm[cur][tid - off];
    sm[cur ^ 1][tid] = a;
    cur ^= 1;
    __syncthreads();
  }
  if (i < n) row_start[i] = sm[cur][tid] - v;     // exclusive
  if (tid == SCAN_B - 1) blksum[blockIdx.x] = sm[cur][tid];
}

// Serial exclusive scan of the 98 block sums (single thread; trivial).
__global__ void scan2_kernel(int* __restrict__ blksum, int nb) {
  if (threadIdx.x == 0 && blockIdx.x == 0) {
    int run = 0;
    for (int b = 0; b < nb; ++b) { int t = blksum[b]; blksum[b] = run; run += t; }
  }
}

// Add block offsets; also dinv = rsqrt(cnt+1)  (+1 = self-loop, always > 0).
__global__ void scan3_kernel(int* __restrict__ row_start, const int* __restrict__ blksum,
                             const int* __restrict__ cnt, float* __restrict__ dinv, int n) {
  int i = blockIdx.x * blockDim.x + threadIdx.x;
  if (i >= n) return;
  row_start[i] += blksum[i / SCAN_B];
  dinv[i] = rsqrtf((float)cnt[i] + 1.0f);
}

// csr[pos] = src, pos via atomic cursor on row_start. AFTER this kernel,
// row_start[r] == end of row r; start = end - cnt[r]. No rebuild needed.
__global__ void fill_kernel(const int* __restrict__ src, const int* __restrict__ dst,
                            int* __restrict__ row_start, int* __restrict__ csr, int E) {
  int stride = gridDim.x * blockDim.x;
  for (int e = blockIdx.x * blockDim.x + threadIdx.x; e < E; e += stride) {
    int pos = atomicAdd(&row_start[dst[e]], 1);
    csr[pos] = src[e];
  }
}

// h[i][j] = sum_k x[i][k] * W[k][j]   (K=128, J=32). One thread per output;
// 32 consecutive lanes share one x row; W staged in LDS.
__global__ void gemm1_kernel(const float* __restrict__ x, const float* __restrict__ W,
                             float* __restrict__ h, int n) {
  __shared__ float Wl[FIN * H];
  for (int t = threadIdx.x; t < FIN * H; t += blockDim.x) Wl[t] = W[t];
  __syncthreads();
  int t = blockIdx.x * blockDim.x + threadIdx.x;
  int i = t >> 5, j = t & 31;
  if (i >= n) return;
  const float4* xr = (const float4*)(x + (size_t)i * FIN);
  float acc = 0.f;
  #pragma unroll 8
  for (int k4 = 0; k4 < FIN / 4; ++k4) {
    float4 v = xr[k4];
    acc += v.x * Wl[(k4 * 4 + 0) * H + j];
    acc += v.y * Wl[(k4 * 4 + 1) * H + j];
    acc += v.z * Wl[(k4 * 4 + 2) * H + j];
    acc += v.w * Wl[(k4 * 4 + 3) * H + j];
  }
  h[t] = acc;
}

// h2[i][j] = sum_k a[i][k] * W[k][j]   (K=32, J=32)
__global__ void gemm2_kernel(const float* __restrict__ a, const float* __restrict__ W,
                             float* __restrict__ h, int n) {
  __shared__ float Wl[H * H];
  for (int t = threadIdx.x; t < H * H; t += blockDim.x) Wl[t] = W[t];
  __syncthreads();
  int t = blockIdx.x * blockDim.x + threadIdx.x;
  int i = t >> 5, j = t & 31;
  if (i >= n) return;
  const float4* ar = (const float4*)(a + (size_t)i * H);
  float acc = 0.f;
  #pragma unroll
  for (int k4 = 0; k4 < H / 4; ++k4) {
    float4 v = ar[k4];
    acc += v.x * Wl[(k4 * 4 + 0) * H + j];
    acc += v.y * Wl[(k4 * 4 + 1) * H + j];
    acc += v.z * Wl[(k4 * 4 + 2) * H + j];
    acc += v.w * Wl[(k4 * 4 + 3) * H + j];
  }
  h[t] = acc;
}

// Row-gather aggregation: 32-lane group per dst row r, lane j = feature.
// acc_j = sum_{s in row} h[s][j]*dinv[s];  out = relu(acc*di + h[r]*di^2 + b).
// 4x unroll keeps 4 independent 128B line-gathers in flight per group.
__global__ void gather1_kernel(const int* __restrict__ csr, const int* __restrict__ cnt,
                               const int* __restrict__ rend, const float* __restrict__ dinv,
                               const float* __restrict__ h, const float* __restrict__ b,
                               float* __restrict__ a1, int n) {
  int t = blockIdx.x * blockDim.x + threadIdx.x;
  int r = t >> 5, j = t & 31;
  if (r >= n) return;
  int end = rend[r];
  int k = end - cnt[r];
  float acc = 0.f;
  for (; k + 4 <= end; k += 4) {
    int s0 = csr[k], s1 = csr[k + 1], s2 = csr[k + 2], s3 = csr[k + 3];
    float v0 = h[s0 * H + j], v1 = h[s1 * H + j], v2 = h[s2 * H + j], v3 = h[s3 * H + j];
    acc += v0 * dinv[s0]; acc += v1 * dinv[s1];
    acc += v2 * dinv[s2]; acc += v3 * dinv[s3];
  }
  for (; k < end; ++k) { int s = csr[k]; acc += h[s * H + j] * dinv[s]; }
  float di = dinv[r];
  float v = acc * di + h[t] * di * di + b[j];   // t == r*H+j
  a1[t] = fmaxf(v, 0.f);
}

// Same gather over h2, fused with the FC scorer: out[r] = sum_j relu(.)*Wfc[j] + bfc.
__global__ void gather2_kernel(const int* __restrict__ csr, const int* __restrict__ cnt,
                               const int* __restrict__ rend, const float* __restrict__ dinv,
                               const float* __restrict__ h2, const float* __restrict__ b2,
                               const float* __restrict__ Wfc, const float* __restrict__ bfc,
                               float* __restrict__ out, int n) {
  int t = blockIdx.x * blockDim.x + threadIdx.x;
  int r = t >> 5, j = t & 31;
  if (r >= n) return;
  int end = rend[r];
  int k = end - cnt[r];
  float acc = 0.f;
  for (; k + 4 <= end; k += 4) {
    int s0 = csr[k], s1 = csr[k + 1], s2 = csr[k + 2], s3 = csr[k + 3];
    float v0 = h2[s0 * H + j], v1 = h2[s1 * H + j], v2 = h2[s2 * H + j], v3 = h2[s3 * H + j];
    acc += v0 * dinv[s0]; acc += v1 * dinv[s1];
    acc += v2 * dinv[s2]; acc += v3 * dinv[s3];
  }
  for (; k < end; ++k) { int s = csr[k]; acc += h2[s * H + j] * dinv[s]; }
  float di = dinv[r];
  float v = acc * di + h2[t] * di * di + b2[j];
  v = fmaxf(v, 0.f) * Wfc[j];
  #pragma unroll
  for (int m = 16; m; m >>= 1) v += __shfl_xor(v, m, 32);
  if (j == 0) out[r] = v + bfc[0];
}

extern "C" void kernel_launch(void* const* d_in, const int* in_sizes, int n_in,
                              void* d_out, int out_size, void* d_ws, size_t ws_size,
                              hipStream_t stream) {
  const float* x   = (const float*)d_in[0];
  const int*   ei  = (const int*)d_in[1];
  const float* W1  = (const float*)d_in[2];
  const float* b1  = (const float*)d_in[3];
  const float* W2  = (const float*)d_in[4];
  const float* b2  = (const float*)d_in[5];
  const float* Wfc = (const float*)d_in[6];
  const float* bfc = (const float*)d_in[7];
  float* out = (float*)d_out;

  const int E = in_sizes[1] / 2;
  const int* src = ei;
  const int* dst = ei + E;

  // ws layout (39.2 MB, same proven footprint):
  // [csr E int | cnt N int | row_start N int | dinv N f32 | h N*H f32 | a1 N*H f32]
  // blksum (98 ints) parked at the head of a1 (a1 first written by gather1, after scans).
  char* w = (char*)d_ws;
  int*   csr       = (int*)w;                    w += (size_t)E * 4;
  int*   cnt       = (int*)w;                    w += (size_t)NN * 4;
  int*   row_start = (int*)w;                    w += (size_t)NN * 4;
  float* dinv      = (float*)w;                  w += (size_t)NN * 4;
  float* h         = (float*)w;                  w += (size_t)NN * H * 4;
  float* a1        = (float*)w;
  int*   blksum    = (int*)a1;

  const int nb_nh = (NN * H + 255) / 256;
  const int nb_n  = (NN + 255) / 256;

  zero_int_kernel<<<nb_n, 256, 0, stream>>>(cnt, NN);
  hist_kernel<<<2048, 256, 0, stream>>>(dst, cnt, E);
  scan1_kernel<<<SCAN_NB, SCAN_B, 0, stream>>>(cnt, row_start, blksum, NN);
  scan2_kernel<<<1, 64, 0, stream>>>(blksum, SCAN_NB);
  scan3_kernel<<<nb_n, 256, 0, stream>>>(row_start, blksum, cnt, dinv, NN);
  fill_kernel<<<2048, 256, 0, stream>>>(src, dst, row_start, csr, E);
  gemm1_kernel<<<nb_nh, 256, 0, stream>>>(x, W1, h, NN);
  gather1_kernel<<<nb_nh, 256, 0, stream>>>(csr, cnt, row_start, dinv, h, b1, a1, NN);
  gemm2_kernel<<<nb_nh, 256, 0, stream>>>(a1, W2, h, NN);  // h := h2
  gather2_kernel<<<nb_nh, 256, 0, stream>>>(csr, cnt, row_start, dinv, h, b2, Wfc, bfc, out, NN);
}